// Round 4
// baseline (5877.649 us; speedup 1.0000x reference)
//
#include <hip/hip_runtime.h>

// LSTM char-RNN forward: batch=1024, T=512, UNITS=256, NUM_CHARS=128.
// R4: MFMA weight-stationary. 256 blocks = 64 row-groups (M=16) x 4
// column-splits (64 units). Wh slice per block = 64 VGPRs/lane (register-
// resident -> zero per-step weight traffic). Per step: 16x
// mfma_f32_16x16x32_f16 per wave, gates in fp32, h-slices exchanged via L2
// (double-buffered, agent-scope release/acquire flags). fp16 weights/h =
// R1-validated numerics. A/B frag k-permutation cancels (identical packing
// formula both sides); only m/n/C layouts (m89-verified) matter.

#define TSTEPS  512
#define UNITS   256
#define NCHAR   128
#define G4      1024

typedef float    f32x4 __attribute__((ext_vector_type(4)));
typedef _Float16 f16x8 __attribute__((ext_vector_type(8)));

union FU { uint4 u4; f16x8 h8; _Float16 h[8]; };

__device__ __forceinline__ float fast_rcp(float x) {
#if __has_builtin(__builtin_amdgcn_rcpf)
  return __builtin_amdgcn_rcpf(x);
#else
  return 1.0f / x;
#endif
}
__device__ __forceinline__ float sigm(float x)  { return fast_rcp(1.0f + __expf(-x)); }
__device__ __forceinline__ float tanhx(float x) { return 2.0f * fast_rcp(1.0f + __expf(-2.0f * x)) - 1.0f; }

// ---- Prep: WhB = Wh in fp16 B-fragment stream order.
// idx = ((cc*16 + tile)*8 + kk)*64 + lane ; lane holds 8 fp16 along K.
// n_local = tile*16 + (lane&15); gate = n&3; unit = cc*64 + (n>>2);
// k = kk*32 + (lane>>4)*8 + j.  (k-permutation is consistent with A-pack.)
__global__ void prep_whB(const float* __restrict__ Wh, uint4* __restrict__ WhB) {
  int idx = blockIdx.x * blockDim.x + threadIdx.x;    // 0..32767
  int l    = idx & 63;
  int kk   = (idx >> 6) & 7;
  int tile = (idx >> 9) & 15;
  int cc   = idx >> 13;
  int n    = tile * 16 + (l & 15);
  int gate = n & 3;
  int ug   = cc * 64 + (n >> 2);
  int col  = gate * 256 + ug;
  int kbase = kk * 32 + (l >> 4) * 8;
  FU p;
#pragma unroll
  for (int j = 0; j < 8; ++j)
    p.h[j] = (_Float16)Wh[(kbase + j) * G4 + col];
  WhB[idx] = p.u4;
}

// ---- Prep: Wxbg[ch][u] = float4(i,f,g,o) = Wx[ch][gate*256+u] + b
__global__ void prep_wx(const float* __restrict__ Wx, const float* __restrict__ bias,
                        float4* __restrict__ Wxbg) {
  int idx = blockIdx.x * blockDim.x + threadIdx.x;    // 0..32767
  int u  = idx & (UNITS - 1);
  int ch = idx >> 8;
  const float* r = Wx + ch * G4;
  float4 o;
  o.x = r[0 * UNITS + u] + bias[0 * UNITS + u];
  o.y = r[1 * UNITS + u] + bias[1 * UNITS + u];
  o.z = r[2 * UNITS + u] + bias[2 * UNITS + u];
  o.w = r[3 * UNITS + u] + bias[3 * UNITS + u];
  Wxbg[idx] = o;
}

// ---- Main: 256 blocks x 512 threads. block = (g = bid&63, c = bid>>6).
__global__ __launch_bounds__(512, 1) void lstm_mfma(
    const int* __restrict__ inp, const uint4* __restrict__ WhB,
    const float4* __restrict__ Wxbg, const float* __restrict__ Wd,
    const float* __restrict__ bd, float* __restrict__ out,
    _Float16* __restrict__ hx, int* __restrict__ flags) {
  __shared__ __align__(16) uint4 hfrag[512];     // 8 KB: h_t in A-frag order
  __shared__ float zbuf[16 * 264];               // 16.9 KB z (and h_f32 in epilogue)
  __shared__ float lgts[16 * 132];               // 8.4 KB logits
  __shared__ int   chs[16];
  __shared__ float rmax[16], rsum[16];

  const int tid  = threadIdx.x;
  const int lane = tid & 63;
  const int wv   = tid >> 6;          // 0..7
  const int g    = blockIdx.x & 63;
  const int c    = blockIdx.x >> 6;
  const int row0 = g * 16;

  // ---- Weight fragments for tiles {2wv, 2wv+1}: 16 uint4 = 64 VGPRs
  FU wf0[8], wf1[8];
#pragma unroll
  for (int kk = 0; kk < 8; ++kk) {
    wf0[kk].u4 = WhB[((c * 16 + 2 * wv)     * 8 + kk) * 64 + lane];
    wf1[kk].u4 = WhB[((c * 16 + 2 * wv + 1) * 8 + kk) * 64 + lane];
  }
#pragma unroll
  for (int kk = 0; kk < 8; ++kk) {
    asm volatile("" : "+v"(wf0[kk].u4.x), "+v"(wf0[kk].u4.y), "+v"(wf0[kk].u4.z), "+v"(wf0[kk].u4.w));
    asm volatile("" : "+v"(wf1[kk].u4.x), "+v"(wf1[kk].u4.y), "+v"(wf1[kk].u4.z), "+v"(wf1[kk].u4.w));
  }

  hfrag[tid] = uint4{0u, 0u, 0u, 0u};            // h_0 = 0

  // gate-phase mapping: row gr, units gu and gu+32
  const int gr = tid >> 5;
  const int gu = tid & 31;
  float cst0 = 0.f, cst1 = 0.f;

  __syncthreads();

  for (int t = 0; t < TSTEPS; ++t) {
    if (t > 0) {
      if (tid < 4) {
        int guard = 0;
        while (__hip_atomic_load(&flags[g * 4 + tid], __ATOMIC_ACQUIRE,
                                 __HIP_MEMORY_SCOPE_AGENT) < t) {
          __builtin_amdgcn_s_sleep(2);
          if (++guard > (1 << 26)) break;
        }
      }
      __syncthreads();
      // gather h_t (4 slices x 2KB) -> scatter into A-frag LDS
      {
        const int par = t & 1;
        const int s   = tid >> 7;
        const int idx = tid & 127;
        uint4 v = ((const uint4*)hx)[(par * 256 + g * 4 + s) * 128 + idx];
        int r  = idx >> 3;
        int k0 = s * 64 + (idx & 7) * 8;
        int kk = k0 >> 5, q = (k0 & 31) >> 3;
        *(uint4*)((char*)hfrag + kk * 1024 + (q * 16 + r) * 16) = v;
      }
      __syncthreads();
    }
    if (tid < 16) chs[tid] = inp[(row0 + tid) * TSTEPS + t];

    // ---- MFMA: z tiles 2wv, 2wv+1 over K=256 (8 chained mfma)
    f32x4 acc0 = {0.f, 0.f, 0.f, 0.f}, acc1 = {0.f, 0.f, 0.f, 0.f};
#pragma unroll
    for (int kk = 0; kk < 8; ++kk) {
      FU a; a.u4 = hfrag[kk * 64 + lane];
      acc0 = __builtin_amdgcn_mfma_f32_16x16x32_f16(a.h8, wf0[kk].h8, acc0, 0, 0, 0);
      acc1 = __builtin_amdgcn_mfma_f32_16x16x32_f16(a.h8, wf1[kk].h8, acc1, 0, 0, 0);
    }
    // C layout: col = lane&15, row = (lane>>4)*4 + reg
    {
      const int cq = lane >> 4, cn = lane & 15;
#pragma unroll
      for (int reg = 0; reg < 4; ++reg) {
        zbuf[(cq * 4 + reg) * 264 + (2 * wv)     * 16 + cn] = acc0[reg];
        zbuf[(cq * 4 + reg) * 264 + (2 * wv + 1) * 16 + cn] = acc1[reg];
      }
    }
    __syncthreads();

    // ---- gates: thread -> (row gr, units gu, gu+32); z cols = u_local*4+gate
    {
      const int ch = chs[gr];
      _Float16* ho = hx + ((size_t)(((t + 1) & 1) * 256 + g * 4 + c)) * 1024;

      float4 z0 = *(const float4*)&zbuf[gr * 264 + gu * 4];
      float4 xb0 = Wxbg[ch * 256 + c * 64 + gu];
      float i0 = sigm(z0.x + xb0.x), f0 = sigm(z0.y + xb0.y);
      float g0 = tanhx(z0.z + xb0.z), o0 = sigm(z0.w + xb0.w);
      cst0 = f0 * cst0 + i0 * g0;
      float h0 = o0 * tanhx(cst0);
      ho[gr * 64 + gu] = (_Float16)h0;

      float4 z1 = *(const float4*)&zbuf[gr * 264 + (gu + 32) * 4];
      float4 xb1 = Wxbg[ch * 256 + c * 64 + gu + 32];
      float i1 = sigm(z1.x + xb1.x), f1 = sigm(z1.y + xb1.y);
      float g1 = tanhx(z1.z + xb1.z), o1 = sigm(z1.w + xb1.w);
      cst1 = f1 * cst1 + i1 * g1;
      float h1 = o1 * tanhx(cst1);
      ho[gr * 64 + gu + 32] = (_Float16)h1;
    }
    __syncthreads();   // drains vmcnt -> all publishes in L2
    if (tid == 0) {
      __threadfence();
      __hip_atomic_store(&flags[g * 4 + c], t + 1, __ATOMIC_RELEASE,
                         __HIP_MEMORY_SCOPE_AGENT);
    }
  }

  if (c != 0) return;

  // ---- Epilogue (c==0): gather h_T as fp32 into zbuf, then logits+softmax
  if (tid < 4) {
    int guard = 0;
    while (__hip_atomic_load(&flags[g * 4 + tid], __ATOMIC_ACQUIRE,
                             __HIP_MEMORY_SCOPE_AGENT) < TSTEPS) {
      __builtin_amdgcn_s_sleep(2);
      if (++guard > (1 << 26)) break;
    }
  }
  __syncthreads();
  {
    const int par = TSTEPS & 1;   // 0
    const int s   = tid >> 7;
    const int idx = tid & 127;
    FU v; v.u4 = ((const uint4*)hx)[(par * 256 + g * 4 + s) * 128 + idx];
    int r  = idx >> 3;
    int k0 = s * 64 + (idx & 7) * 8;
#pragma unroll
    for (int i = 0; i < 8; ++i)
      zbuf[r * 264 + k0 + i] = (float)v.h[i];
  }
  __syncthreads();
  {
    const int j  = tid & 127;
    const int rb = (tid >> 7) * 4;
    float lacc[4];
#pragma unroll
    for (int ii = 0; ii < 4; ++ii) lacc[ii] = bd[j];
    for (int k = 0; k < 256; ++k) {
      float w = Wd[k * NCHAR + j];
#pragma unroll
      for (int ii = 0; ii < 4; ++ii)
        lacc[ii] += zbuf[(rb + ii) * 264 + k] * w;
    }
#pragma unroll
    for (int ii = 0; ii < 4; ++ii) lgts[(rb + ii) * 132 + j] = lacc[ii];
  }
  __syncthreads();
  if (tid < 16) {
    const int r = tid;
    float m = -1e30f;
    for (int j = 0; j < NCHAR; ++j) m = fmaxf(m, lgts[r * 132 + j]);
    float s = 0.f;
    for (int j = 0; j < NCHAR; ++j) s += __expf(lgts[r * 132 + j] - m);
    rmax[r] = m;
    rsum[r] = fast_rcp(s);
  }
  __syncthreads();
  {
    const int j  = tid & 127;
    const int rb = (tid >> 7) * 4;
#pragma unroll
    for (int ii = 0; ii < 4; ++ii) {
      int r = rb + ii;
      out[(row0 + r) * NCHAR + j] = __expf(lgts[r * 132 + j] - rmax[r]) * rsum[r];
    }
  }
}

extern "C" void kernel_launch(void* const* d_in, const int* in_sizes, int n_in,
                              void* d_out, int out_size, void* d_ws, size_t ws_size,
                              hipStream_t stream) {
  const int*   inp = (const int*)d_in[0];
  const float* Wx  = (const float*)d_in[1];
  const float* Wh  = (const float*)d_in[2];
  const float* bia = (const float*)d_in[3];
  const float* Wd  = (const float*)d_in[4];
  const float* bd  = (const float*)d_in[5];

  uint4*     WhB   = (uint4*)d_ws;                               // 512 KB
  float4*    Wxbg  = (float4*)((char*)d_ws + (512 << 10));       // 512 KB
  _Float16*  hx    = (_Float16*)((char*)d_ws + (1 << 20));       // 1 MB
  int*       flags = (int*)((char*)d_ws + (2 << 20));            // 1 KB

  hipMemsetAsync(flags, 0, 1024, stream);
  prep_whB<<<128, 256, 0, stream>>>(Wh, WhB);
  prep_wx<<<128, 256, 0, stream>>>(Wx, bia, Wxbg);
  lstm_mfma<<<256, 512, 0, stream>>>(inp, WhB, Wxbg, Wd, bd, (float*)d_out,
                                     hx, flags);
}

// Round 5
// 1608.077 us; speedup vs baseline: 3.6551x; 3.6551x over previous
//
#include <hip/hip_runtime.h>

// LSTM char-RNN forward: batch=1024, T=512, UNITS=256, NUM_CHARS=128.
// R5: R4's weight-stationary MFMA exchange design (correctness-validated),
// with the fence disaster removed. 2-way column split: 128 blocks x 1024
// threads; block (g = bid&63, c = bid>>6) owns rows g*16..+16 and units
// c*128..+128. Weights = 16 B-frag uint4/thread (AGPR-resident, R4-proven).
// Exchange: h half-slices as agent-scope RELAXED atomics (coherence-point
// routed -> XCD-placement independent); ordering via __syncthreads' vmcnt(0)
// drain before the relaxed flag store. No threadfence / wbl2 / L2-inv.

#define TSTEPS 512
#define UNITS  256
#define NCHAR  128
#define G4     1024
#define ZS     516   // zbuf row stride (4-pad: 2-way LDS aliasing only)

typedef float    f32x4 __attribute__((ext_vector_type(4)));
typedef _Float16 f16x8 __attribute__((ext_vector_type(8)));

union FU { uint4 u4; f16x8 h8; _Float16 h[8]; };
union HP { unsigned int u; _Float16 f[2]; };

__device__ __forceinline__ float fast_rcp(float x) {
#if __has_builtin(__builtin_amdgcn_rcpf)
  return __builtin_amdgcn_rcpf(x);
#else
  return 1.0f / x;
#endif
}
__device__ __forceinline__ float sigm(float x)  { return fast_rcp(1.0f + __expf(-x)); }
__device__ __forceinline__ float tanhx(float x) { return 2.0f * fast_rcp(1.0f + __expf(-2.0f * x)) - 1.0f; }

// ---- Prep: WhB = Wh fp16 B-fragment stream. idx=((cc*32+tile)*8+kk)*64+l.
// n = tile*16+(l&15); gate=n&3; unit = cc*128 + (n>>2); col = gate*256+unit;
// k = kk*32 + (l>>4)*8 + j.   (k-mapping identical to A-side -> cancels.)
__global__ void prep_whB(const float* __restrict__ Wh, uint4* __restrict__ WhB) {
  int idx = blockIdx.x * blockDim.x + threadIdx.x;    // 0..32767
  int l    = idx & 63;
  int kk   = (idx >> 6) & 7;
  int tile = (idx >> 9) & 31;
  int cc   = idx >> 14;
  int n    = tile * 16 + (l & 15);
  int gate = n & 3;
  int col  = gate * 256 + cc * 128 + (n >> 2);
  int kb   = kk * 32 + (l >> 4) * 8;
  FU p;
#pragma unroll
  for (int j = 0; j < 8; ++j)
    p.h[j] = (_Float16)Wh[(kb + j) * G4 + col];
  WhB[idx] = p.u4;
}

// ---- Prep: Wxbg[ch][u] = float4(i,f,g,o) = Wx[ch][gate*256+u] + b
__global__ void prep_wx(const float* __restrict__ Wx, const float* __restrict__ bias,
                        float4* __restrict__ Wxbg) {
  int idx = blockIdx.x * blockDim.x + threadIdx.x;    // 0..32767
  int u  = idx & (UNITS - 1);
  int ch = idx >> 8;
  const float* r = Wx + ch * G4;
  float4 o;
  o.x = r[0 * UNITS + u] + bias[0 * UNITS + u];
  o.y = r[1 * UNITS + u] + bias[1 * UNITS + u];
  o.z = r[2 * UNITS + u] + bias[2 * UNITS + u];
  o.w = r[3 * UNITS + u] + bias[3 * UNITS + u];
  Wxbg[idx] = o;
}

// A-frag LDS byte address for h element (row m, k): hfrag layout from R4.
__device__ __forceinline__ int afrag_addr(int k, int m) {
  return ((k >> 5) << 10) + (((((k >> 3) & 3) << 4) + m) << 4) + ((k & 7) << 1);
}

// ---- Main: 128 blocks x 1024 threads. (g = bid&63, c = bid>>6).
__global__ __launch_bounds__(1024) void lstm_mfma(
    const int* __restrict__ inp, const uint4* __restrict__ WhB,
    const float4* __restrict__ Wxbg, const float* __restrict__ Wd,
    const float* __restrict__ bd, float* __restrict__ out,
    unsigned int* __restrict__ hxu, int* __restrict__ flags) {
  __shared__ __align__(16) uint4 hfrag[512];     // 8 KB: h_t A-frags (full K=256)
  __shared__ float zbuf[16 * ZS];                // 33 KB: z rows [16][512+pad]
  __shared__ float lgts[16 * 132];               // 8.4 KB
  __shared__ float rmax[16], rsum[16];

  const int tid  = threadIdx.x;
  const int lane = tid & 63;
  const int wv   = tid >> 6;          // 0..15 == batch row within group
  const int bid  = blockIdx.x;
  const int g    = bid & 63;
  const int c    = bid >> 6;          // column half
  const int sib  = bid ^ 64;          // same-XCD sibling (perf heuristic only)
  const int row0 = g * 16;

  // ---- Weight B-frags: 2 tiles/wave x 8 kk = 16 uint4 = 64 regs (AGPR ok)
  FU wf0[8], wf1[8];
#pragma unroll
  for (int kk = 0; kk < 8; ++kk) {
    wf0[kk].u4 = WhB[((c * 32 + wv * 2)     * 8 + kk) * 64 + lane];
    wf1[kk].u4 = WhB[((c * 32 + wv * 2 + 1) * 8 + kk) * 64 + lane];
  }
#pragma unroll
  for (int kk = 0; kk < 8; ++kk) {
    asm volatile("" : "+v"(wf0[kk].u4.x), "+v"(wf0[kk].u4.y), "+v"(wf0[kk].u4.z), "+v"(wf0[kk].u4.w));
    asm volatile("" : "+v"(wf1[kk].u4.x), "+v"(wf1[kk].u4.y), "+v"(wf1[kk].u4.z), "+v"(wf1[kk].u4.w));
  }

  if (tid < 512) hfrag[tid] = uint4{0u, 0u, 0u, 0u};   // h_0 = 0
  float cst0 = 0.f, cst1 = 0.f;
  __syncthreads();

  for (int t = 0; t < TSTEPS; ++t) {
    // prefetch char + input-projection (hidden under wait/MFMA)
    int    ch  = inp[(row0 + wv) * TSTEPS + t];
    float4 xb0 = Wxbg[ch * 256 + c * 128 + lane];
    float4 xb1 = Wxbg[ch * 256 + c * 128 + 64 + lane];

    if (t > 0) {
      if (tid == 0) {
        int guard = 0;
        while (__hip_atomic_load(&flags[sib], __ATOMIC_ACQUIRE,
                                 __HIP_MEMORY_SCOPE_AGENT) < t) {
          __builtin_amdgcn_s_sleep(2);
          if (++guard > (1 << 25)) break;
        }
      }
      __syncthreads();
      // gather sibling half of h_t (1 packed dword/thread), scatter to A-frags
      const int par = t & 1;
      const int cs  = 1 - c;
      HP v;
      v.u = __hip_atomic_load(&hxu[((par * 64 + g) * 2 + cs) * 1024 + tid],
                              __ATOMIC_RELAXED, __HIP_MEMORY_SCOPE_AGENT);
      const int r  = tid >> 6, up = tid & 63;
      const int ka = cs * 128 + up;
      *(_Float16*)((char*)hfrag + afrag_addr(ka,      r)) = v.f[0];
      *(_Float16*)((char*)hfrag + afrag_addr(ka + 64, r)) = v.f[1];
    }
    __syncthreads();   // hfrag complete; zbuf free

    // ---- MFMA: tiles 2wv, 2wv+1 over K=256
    f32x4 acc0 = {0.f, 0.f, 0.f, 0.f}, acc1 = {0.f, 0.f, 0.f, 0.f};
#pragma unroll
    for (int kk = 0; kk < 8; ++kk) {
      FU a; a.u4 = hfrag[kk * 64 + lane];
      acc0 = __builtin_amdgcn_mfma_f32_16x16x32_f16(a.h8, wf0[kk].h8, acc0, 0, 0, 0);
      acc1 = __builtin_amdgcn_mfma_f32_16x16x32_f16(a.h8, wf1[kk].h8, acc1, 0, 0, 0);
    }
    {
      const int cq = lane >> 4, cn = lane & 15;   // C: row=(lane>>4)*4+reg, col=cn
#pragma unroll
      for (int reg = 0; reg < 4; ++reg) {
        zbuf[(cq * 4 + reg) * ZS + (wv * 2)     * 16 + cn] = acc0[reg];
        zbuf[(cq * 4 + reg) * ZS + (wv * 2 + 1) * 16 + cn] = acc1[reg];
      }
    }
    __syncthreads();   // zbuf ready

    // ---- gates: thread = (row wv, units u0 = c*128+lane, u1 = u0+64)
    {
      float4 z0 = *(const float4*)&zbuf[wv * ZS + lane * 4];          // n = 4*lane
      float4 z1 = *(const float4*)&zbuf[wv * ZS + lane * 4 + 256];    // n = 4*(lane+64)
      float i0 = sigm(z0.x + xb0.x), f0 = sigm(z0.y + xb0.y);
      float g0 = tanhx(z0.z + xb0.z), o0 = sigm(z0.w + xb0.w);
      cst0 = f0 * cst0 + i0 * g0;
      float h0 = o0 * tanhx(cst0);
      float i1 = sigm(z1.x + xb1.x), f1 = sigm(z1.y + xb1.y);
      float g1 = tanhx(z1.z + xb1.z), o1 = sigm(z1.w + xb1.w);
      cst1 = f1 * cst1 + i1 * g1;
      float h1 = o1 * tanhx(cst1);

      HP p; p.f[0] = (_Float16)h0; p.f[1] = (_Float16)h1;
      // own half straight to LDS A-frags (no memory round trip)
      const int ka = c * 128 + lane;
      *(_Float16*)((char*)hfrag + afrag_addr(ka,      wv)) = p.f[0];
      *(_Float16*)((char*)hfrag + afrag_addr(ka + 64, wv)) = p.f[1];
      // publish to sibling: relaxed agent atomic (coherence-point routed)
      const int par1 = (t + 1) & 1;
      __hip_atomic_store(&hxu[((par1 * 64 + g) * 2 + c) * 1024 + tid], p.u,
                         __ATOMIC_RELAXED, __HIP_MEMORY_SCOPE_AGENT);
    }
    __syncthreads();   // drains vmcnt(0): all payload at coherence point
    if (tid == 0)
      __hip_atomic_store(&flags[bid], t + 1, __ATOMIC_RELAXED,
                         __HIP_MEMORY_SCOPE_AGENT);
  }

  if (c != 0) return;

  // ---- Epilogue (c==0): gather full h_T (par=0) -> fp32 zbuf, Wd, softmax
  if (tid == 0) {
    int guard = 0;
    while (__hip_atomic_load(&flags[sib], __ATOMIC_ACQUIRE,
                             __HIP_MEMORY_SCOPE_AGENT) < TSTEPS) {
      __builtin_amdgcn_s_sleep(2);
      if (++guard > (1 << 25)) break;
    }
  }
  __syncthreads();
  {
    const int r = tid >> 6, up = tid & 63;
#pragma unroll
    for (int half = 0; half < 2; ++half) {
      HP v;
      v.u = __hip_atomic_load(&hxu[(g * 2 + half) * 1024 + tid],
                              __ATOMIC_RELAXED, __HIP_MEMORY_SCOPE_AGENT);
      zbuf[r * ZS + half * 128 + up]      = (float)v.f[0];
      zbuf[r * ZS + half * 128 + up + 64] = (float)v.f[1];
    }
  }
  __syncthreads();
  {
    const int j  = tid & 127;
    const int rb = tid >> 7;            // 0..7 -> rows 2rb, 2rb+1
    const int r0 = rb * 2, r1 = r0 + 1;
    float l0 = bd[j], l1 = bd[j];
    for (int k = 0; k < 256; ++k) {
      float w = Wd[k * NCHAR + j];
      l0 += zbuf[r0 * ZS + k] * w;
      l1 += zbuf[r1 * ZS + k] * w;
    }
    lgts[r0 * 132 + j] = l0;
    lgts[r1 * 132 + j] = l1;
  }
  __syncthreads();
  if (tid < 16) {
    const int r = tid;
    float m = -1e30f;
    for (int j = 0; j < NCHAR; ++j) m = fmaxf(m, lgts[r * 132 + j]);
    float s = 0.f;
    for (int j = 0; j < NCHAR; ++j) s += __expf(lgts[r * 132 + j] - m);
    rmax[r] = m;
    rsum[r] = fast_rcp(s);
  }
  __syncthreads();
  {
    const int j  = tid & 127;
    const int rb = tid >> 7;
#pragma unroll
    for (int ii = 0; ii < 2; ++ii) {
      int r = rb * 2 + ii;
      out[(row0 + r) * NCHAR + j] = __expf(lgts[r * 132 + j] - rmax[r]) * rsum[r];
    }
  }
}

extern "C" void kernel_launch(void* const* d_in, const int* in_sizes, int n_in,
                              void* d_out, int out_size, void* d_ws, size_t ws_size,
                              hipStream_t stream) {
  const int*   inp = (const int*)d_in[0];
  const float* Wx  = (const float*)d_in[1];
  const float* Wh  = (const float*)d_in[2];
  const float* bia = (const float*)d_in[3];
  const float* Wd  = (const float*)d_in[4];
  const float* bd  = (const float*)d_in[5];

  uint4*        WhB   = (uint4*)d_ws;                            // 512 KB
  float4*       Wxbg  = (float4*)((char*)d_ws + (512 << 10));    // 512 KB
  unsigned int* hxu   = (unsigned int*)((char*)d_ws + (1 << 20));// 1 MB
  int*          flags = (int*)((char*)d_ws + (2 << 20));         // 512 B

  hipMemsetAsync(flags, 0, 512, stream);
  prep_whB<<<128, 256, 0, stream>>>(Wh, WhB);
  prep_wx<<<128, 256, 0, stream>>>(Wx, bia, Wxbg);
  lstm_mfma<<<128, 1024, 0, stream>>>(inp, WhB, Wxbg, Wd, bd, (float*)d_out,
                                      hxu, flags);
}

// Round 8
// 1096.744 us; speedup vs baseline: 5.3592x; 1.4662x over previous
//
#include <hip/hip_runtime.h>

// LSTM char-RNN forward: batch=1024, T=512, UNITS=256, NUM_CHARS=128.
// R8 = R5 (last-known-good, 1608us) + fused exchange. The h-exchange word
// is a u64 (tag << 32 | fp16x2 payload) stored/loaded with R5's proven
// agent-scope RELAXED atomics; consumer polls its own word for tag==t
// (equality -> poison/stale-proof). This collapses R5's serialized
// flag-publish -> detect -> gather (3 coherence-point round trips) into 1.
// Also: K-split MFMA (own-half K before the poll). No flags, no memset, no
// inline asm beyond the weight pin. Same arithmetic order as R5 -> same
// absmax (6.1e-5).

#define TSTEPS 512
#define UNITS  256
#define NCHAR  128
#define G4     1024
#define ZS     516   // zbuf row stride

typedef float    f32x4 __attribute__((ext_vector_type(4)));
typedef _Float16 f16x8 __attribute__((ext_vector_type(8)));

union FU { uint4 u4; f16x8 h8; _Float16 h[8]; };
union HP { unsigned int u; _Float16 f[2]; };

__device__ __forceinline__ float fast_rcp(float x) {
#if __has_builtin(__builtin_amdgcn_rcpf)
  return __builtin_amdgcn_rcpf(x);
#else
  return 1.0f / x;
#endif
}
__device__ __forceinline__ float sigm(float x)  { return fast_rcp(1.0f + __expf(-x)); }
__device__ __forceinline__ float tanhx(float x) { return 2.0f * fast_rcp(1.0f + __expf(-2.0f * x)) - 1.0f; }

// ---- Prep: WhB = Wh fp16 B-fragment stream. idx=((cc*32+tile)*8+kk)*64+l.
// n = tile*16+(l&15); gate=n&3; col = gate*256 + cc*128 + (n>>2);
// k = kk*32 + (l>>4)*8 + j.   (k-mapping identical to A-side -> cancels.)
__global__ void prep_whB(const float* __restrict__ Wh, uint4* __restrict__ WhB) {
  int idx = blockIdx.x * blockDim.x + threadIdx.x;    // 0..32767
  int l    = idx & 63;
  int kk   = (idx >> 6) & 7;
  int tile = (idx >> 9) & 31;
  int cc   = idx >> 14;
  int n    = tile * 16 + (l & 15);
  int gate = n & 3;
  int col  = gate * 256 + cc * 128 + (n >> 2);
  int kb   = kk * 32 + (l >> 4) * 8;
  FU p;
#pragma unroll
  for (int j = 0; j < 8; ++j)
    p.h[j] = (_Float16)Wh[(kb + j) * G4 + col];
  WhB[idx] = p.u4;
}

// ---- Prep: Wxbg[ch][u] = float4(i,f,g,o) = Wx[ch][gate*256+u] + b
__global__ void prep_wx(const float* __restrict__ Wx, const float* __restrict__ bias,
                        float4* __restrict__ Wxbg) {
  int idx = blockIdx.x * blockDim.x + threadIdx.x;    // 0..32767
  int u  = idx & (UNITS - 1);
  int ch = idx >> 8;
  const float* r = Wx + ch * G4;
  float4 o;
  o.x = r[0 * UNITS + u] + bias[0 * UNITS + u];
  o.y = r[1 * UNITS + u] + bias[1 * UNITS + u];
  o.z = r[2 * UNITS + u] + bias[2 * UNITS + u];
  o.w = r[3 * UNITS + u] + bias[3 * UNITS + u];
  Wxbg[idx] = o;
}

// A-frag LDS byte address for h element (row m, k).
__device__ __forceinline__ int afrag_addr(int k, int m) {
  return ((k >> 5) << 10) + (((((k >> 3) & 3) << 4) + m) << 4) + ((k & 7) << 1);
}

// ---- Main: 128 blocks x 1024 threads. (g = bid&63, c = bid>>6).
__global__ __launch_bounds__(1024) void lstm_mfma(
    const int* __restrict__ inp, const uint4* __restrict__ WhB,
    const float4* __restrict__ Wxbg, const float* __restrict__ Wd,
    const float* __restrict__ bd, float* __restrict__ out,
    unsigned long long* __restrict__ hx2) {
  __shared__ __align__(16) uint4 hfrag[512];     // 8 KB: h_t A-frags (K=256)
  __shared__ float zbuf[16 * ZS];                // 33 KB
  __shared__ float lgts[16 * 132];               // 8.4 KB
  __shared__ float rmax[16], rsum[16];

  const int tid  = threadIdx.x;
  const int lane = tid & 63;
  const int wv   = tid >> 6;          // 0..15 == batch row within group
  const int bid  = blockIdx.x;
  const int g    = bid & 63;
  const int c    = bid >> 6;          // column half
  const int row0 = g * 16;

  // ---- Weight B-frags, own-half kk's in slots 0..3, sibling-half in 4..7.
  FU wf0[8], wf1[8];
#pragma unroll
  for (int kx = 0; kx < 8; ++kx) {
    int kk = (kx < 4) ? (c * 4 + kx) : ((1 - c) * 4 + (kx - 4));
    wf0[kx].u4 = WhB[((c * 32 + wv * 2)     * 8 + kk) * 64 + lane];
    wf1[kx].u4 = WhB[((c * 32 + wv * 2 + 1) * 8 + kk) * 64 + lane];
  }
#pragma unroll
  for (int kx = 0; kx < 8; ++kx) {
    asm volatile("" : "+v"(wf0[kx].u4.x), "+v"(wf0[kx].u4.y), "+v"(wf0[kx].u4.z), "+v"(wf0[kx].u4.w));
    asm volatile("" : "+v"(wf1[kx].u4.x), "+v"(wf1[kx].u4.y), "+v"(wf1[kx].u4.z), "+v"(wf1[kx].u4.w));
  }

  if (tid < 512) hfrag[tid] = uint4{0u, 0u, 0u, 0u};   // h_0 = 0
  float cst0 = 0.f, cst1 = 0.f;
  __syncthreads();
  const int kown = c * 4, ksib = (1 - c) * 4;
  const int cs   = 1 - c;

  for (int t = 0; t < TSTEPS; ++t) {
    int    ch  = inp[(row0 + wv) * TSTEPS + t];
    float4 xb0 = Wxbg[ch * 256 + c * 128 + lane];
    float4 xb1 = Wxbg[ch * 256 + c * 128 + 64 + lane];

    // ---- own-half K MFMA first (hides exchange latency); t=0: hfrag = 0
    f32x4 acc0 = {0.f, 0.f, 0.f, 0.f}, acc1 = {0.f, 0.f, 0.f, 0.f};
#pragma unroll
    for (int kx = 0; kx < 4; ++kx) {
      FU a; a.u4 = hfrag[(kown + kx) * 64 + lane];
      acc0 = __builtin_amdgcn_mfma_f32_16x16x32_f16(a.h8, wf0[kx].h8, acc0, 0, 0, 0);
      acc1 = __builtin_amdgcn_mfma_f32_16x16x32_f16(a.h8, wf1[kx].h8, acc1, 0, 0, 0);
    }

    if (t > 0) {
      // ---- fused detect+gather: poll own payload word until tag == t
      const int par = t & 1;
      const unsigned long long* src =
          &hx2[((par * 64 + g) * 2 + cs) * 1024 + tid];
      unsigned long long v;
      long guard = 0;
      do {
        v = __hip_atomic_load(src, __ATOMIC_RELAXED, __HIP_MEMORY_SCOPE_AGENT);
      } while ((unsigned)(v >> 32) != (unsigned)t && ++guard < (1L << 14));
      HP hv; hv.u = (unsigned)v;
      const int r = tid >> 6, up = tid & 63;
      const int ka = cs * 128 + up;
      *(_Float16*)((char*)hfrag + afrag_addr(ka,      r)) = hv.f[0];
      *(_Float16*)((char*)hfrag + afrag_addr(ka + 64, r)) = hv.f[1];
      __syncthreads();
    }

    // ---- sibling-half K MFMA
#pragma unroll
    for (int kx = 0; kx < 4; ++kx) {
      FU a; a.u4 = hfrag[(ksib + kx) * 64 + lane];
      acc0 = __builtin_amdgcn_mfma_f32_16x16x32_f16(a.h8, wf0[4 + kx].h8, acc0, 0, 0, 0);
      acc1 = __builtin_amdgcn_mfma_f32_16x16x32_f16(a.h8, wf1[4 + kx].h8, acc1, 0, 0, 0);
    }
    {
      const int cq = lane >> 4, cn = lane & 15;   // C: row=(lane>>4)*4+reg
#pragma unroll
      for (int reg = 0; reg < 4; ++reg) {
        zbuf[(cq * 4 + reg) * ZS + (wv * 2)     * 16 + cn] = acc0[reg];
        zbuf[(cq * 4 + reg) * ZS + (wv * 2 + 1) * 16 + cn] = acc1[reg];
      }
    }
    __syncthreads();   // zbuf ready

    // ---- gates: thread = (row wv, units u0 = c*128+lane, u1 = u0+64)
    {
      float4 z0 = *(const float4*)&zbuf[wv * ZS + lane * 4];
      float4 z1 = *(const float4*)&zbuf[wv * ZS + lane * 4 + 256];
      float i0 = sigm(z0.x + xb0.x), f0 = sigm(z0.y + xb0.y);
      float g0 = tanhx(z0.z + xb0.z), o0 = sigm(z0.w + xb0.w);
      cst0 = f0 * cst0 + i0 * g0;
      float h0 = o0 * tanhx(cst0);
      float i1 = sigm(z1.x + xb1.x), f1 = sigm(z1.y + xb1.y);
      float g1 = tanhx(z1.z + xb1.z), o1 = sigm(z1.w + xb1.w);
      cst1 = f1 * cst1 + i1 * g1;
      float h1 = o1 * tanhx(cst1);

      HP p; p.f[0] = (_Float16)h0; p.f[1] = (_Float16)h1;
      // own half straight to own-kk A-frags
      const int ka = c * 128 + lane;
      *(_Float16*)((char*)hfrag + afrag_addr(ka,      wv)) = p.f[0];
      *(_Float16*)((char*)hfrag + afrag_addr(ka + 64, wv)) = p.f[1];
      // publish tagged payload (fire-and-forget; self-validating)
      const int par1 = (t + 1) & 1;
      unsigned long long val =
          ((unsigned long long)(unsigned)(t + 1) << 32) | (unsigned long long)p.u;
      __hip_atomic_store(&hx2[((par1 * 64 + g) * 2 + c) * 1024 + tid], val,
                         __ATOMIC_RELAXED, __HIP_MEMORY_SCOPE_AGENT);
    }
    __syncthreads();   // hfrag own-half + zbuf handoff for next iteration
  }

  if (c != 0) return;

  // ---- Epilogue (c==0): poll h_T (tag==TSTEPS, par=0) -> fp32, Wd, softmax
  {
    const int r = tid >> 6, up = tid & 63;
#pragma unroll
    for (int half = 0; half < 2; ++half) {
      const unsigned long long* src = &hx2[(g * 2 + half) * 1024 + tid];
      unsigned long long v;
      long guard = 0;
      do {
        v = __hip_atomic_load(src, __ATOMIC_RELAXED, __HIP_MEMORY_SCOPE_AGENT);
      } while ((unsigned)(v >> 32) != (unsigned)TSTEPS && ++guard < (1L << 14));
      HP hv; hv.u = (unsigned)v;
      zbuf[r * ZS + half * 128 + up]      = (float)hv.f[0];
      zbuf[r * ZS + half * 128 + up + 64] = (float)hv.f[1];
    }
  }
  __syncthreads();
  {
    const int j  = tid & 127;
    const int rb = tid >> 7;            // 0..7 -> rows 2rb, 2rb+1
    const int r0 = rb * 2, r1 = r0 + 1;
    float l0 = bd[j], l1 = bd[j];
    for (int k = 0; k < 256; ++k) {
      float w = Wd[k * NCHAR + j];
      l0 += zbuf[r0 * ZS + k] * w;
      l1 += zbuf[r1 * ZS + k] * w;
    }
    lgts[r0 * 132 + j] = l0;
    lgts[r1 * 132 + j] = l1;
  }
  __syncthreads();
  if (tid < 16) {
    const int r = tid;
    float m = -1e30f;
    for (int j = 0; j < NCHAR; ++j) m = fmaxf(m, lgts[r * 132 + j]);
    float s = 0.f;
    for (int j = 0; j < NCHAR; ++j) s += __expf(lgts[r * 132 + j] - m);
    rmax[r] = m;
    rsum[r] = fast_rcp(s);
  }
  __syncthreads();
  {
    const int j  = tid & 127;
    const int rb = tid >> 7;
#pragma unroll
    for (int ii = 0; ii < 2; ++ii) {
      int r = rb * 2 + ii;
      out[(row0 + r) * NCHAR + j] = __expf(lgts[r * 132 + j] - rmax[r]) * rsum[r];
    }
  }
}

extern "C" void kernel_launch(void* const* d_in, const int* in_sizes, int n_in,
                              void* d_out, int out_size, void* d_ws, size_t ws_size,
                              hipStream_t stream) {
  const int*   inp = (const int*)d_in[0];
  const float* Wx  = (const float*)d_in[1];
  const float* Wh  = (const float*)d_in[2];
  const float* bia = (const float*)d_in[3];
  const float* Wd  = (const float*)d_in[4];
  const float* bd  = (const float*)d_in[5];

  uint4*              WhB  = (uint4*)d_ws;                          // 512 KB
  float4*             Wxbg = (float4*)((char*)d_ws + (512 << 10));  // 512 KB
  unsigned long long* hx2  = (unsigned long long*)((char*)d_ws + (1 << 20)); // 2 MB

  prep_whB<<<128, 256, 0, stream>>>(Wh, WhB);
  prep_wx<<<128, 256, 0, stream>>>(Wx, bia, Wxbg);
  lstm_mfma<<<128, 1024, 0, stream>>>(inp, WhB, Wxbg, Wd, bd, (float*)d_out,
                                      hx2);
}